// Round 4
// baseline (62.826 us; speedup 1.0000x reference)
//
#include <hip/hip_runtime.h>

#define HH 40
#define WW 40
#define NP 36
#define NC 256
#define NB 128
#define IPB 16               // images per block
#define BLK (IPB * NP)       // 576 threads = 9 waves

// Fully fused: each block serves 16 whole images (one batch's channel slice).
// Block redundantly computes its batch's 36 sample records (tiny GEMM; Woff
// is 73 KB -> L2-resident, no extra HBM) into LDS, then gathers with paired
// 8-byte row loads (x-neighbors are adjacent pixels; border folded into wx).
__global__ __launch_bounds__(BLK) void fused_kernel(
    const float* __restrict__ cq, const float* __restrict__ refp,
    const float* __restrict__ fmap, const float* __restrict__ pmap,
    const float* __restrict__ Woff, const float* __restrict__ boff,
    float* __restrict__ out) {
    int b = blockIdx.x >> 4;     // 16 blocks per batch (256/16 images)
    __shared__ float offs[2 * NP];
    __shared__ float4 wrec[NP];
    __shared__ int    irec[NP];

    int j = threadIdx.x;
    if (j < 2 * NP) {
        const float4* w4 = (const float4*)(Woff + j * NC);
        const float4* q4 = (const float4*)(cq + b * NC);  // broadcast across lanes
        float acc = 0.f;
#pragma unroll 8
        for (int k = 0; k < NC / 4; ++k) {
            float4 a = q4[k], ww = w4[k];
            acc = fmaf(a.x, ww.x, acc);
            acc = fmaf(a.y, ww.y, acc);
            acc = fmaf(a.z, ww.z, acc);
            acc = fmaf(a.w, ww.w, acc);
        }
        offs[j] = acc + boff[j];
    }
    __syncthreads();
    if (j < NP) {
        float sx = offs[2 * j + 0] + refp[b * 2 + 0];
        float sy = offs[2 * j + 1] + refp[b * 2 + 1];
        // grid = 2*s - 1 ; pix = s*size - 0.5 ; border clamp
        float x = fminf(fmaxf(sx * (float)WW - 0.5f, 0.f), (float)(WW - 1));
        float y = fminf(fmaxf(sy * (float)HH - 0.5f, 0.f), (float)(HH - 1));
        // clamp x0<=W-2 so (x0, x0+1) is always a valid in-row pair;
        // when x==W-1 exactly this gives wx=1 -> identical value.
        int x0 = min((int)floorf(x), WW - 2);
        int y0 = min((int)floorf(y), HH - 2);
        float wx = x - (float)x0, wy = y - (float)y0;
        wrec[j] = make_float4((1.f - wx) * (1.f - wy), wx * (1.f - wy),
                              (1.f - wx) * wy, wx * wy);
        irec[j] = y0 * WW + x0;
    }
    __syncthreads();

    int ib = threadIdx.x / NP;        // image-in-block 0..15
    int p  = threadIdx.x - ib * NP;   // 0..35
    int img = blockIdx.x * IPB + ib;  // b*256 + c

    float4 w = wrec[p];
    int i00 = irec[p];
    const float* f = fmap + (long)img * (HH * WW) + i00;
    const float* g = pmap + (long)img * (HH * WW) + i00;

    float2 f0, f1, g0, g1;
    __builtin_memcpy(&f0, f, 8);           // pixels (y0, x0..x0+1)
    __builtin_memcpy(&f1, f + WW, 8);      // pixels (y0+1, x0..x0+1)
    __builtin_memcpy(&g0, g, 8);
    __builtin_memcpy(&g1, g + WW, 8);

    float vf = f0.x * w.x + f0.y * w.y + f1.x * w.z + f1.y * w.w;
    float vg = g0.x * w.x + g0.y * w.y + g1.x * w.z + g1.y * w.w;

    long oidx = (long)img * NP + p;
    out[oidx] = vf;
    out[(long)NB * NC * NP + oidx] = vg;
}

extern "C" void kernel_launch(void* const* d_in, const int* in_sizes, int n_in,
                              void* d_out, int out_size, void* d_ws, size_t ws_size,
                              hipStream_t stream) {
    const float* cq   = (const float*)d_in[0];  // (128, 256)
    const float* refp = (const float*)d_in[1];  // (128, 2)
    const float* fmap = (const float*)d_in[2];  // (128, 256, 1600)
    const float* pmap = (const float*)d_in[3];  // (128, 256, 1600)
    const float* Woff = (const float*)d_in[4];  // (72, 256)
    const float* boff = (const float*)d_in[5];  // (72,)
    float* out = (float*)d_out;

    // 65536 images / 16 per block = 4096 blocks.
    fused_kernel<<<(NB * NC) / IPB, BLK, 0, stream>>>(cq, refp, fmap, pmap,
                                                      Woff, boff, out);
}

// Round 5
// 50.544 us; speedup vs baseline: 1.2430x; 1.2430x over previous
//
#include <hip/hip_runtime.h>

#define HH 40
#define WW 40
#define NP 36
#define NC 256
#define NB 128
#define IPB 16               // images per block
#define BLK (IPB * NP)       // 576 threads = 9 waves

// Kernel 1: per-batch offset GEMM + packed bilinear records.
// rec_w[b][p] = 4 bilinear weights; rec_i[b][p] = base pixel offset (i00).
// x0<=W-2, y0<=H-2 clamp folds the border case into wx/wy=1 (identical math),
// so the 4 neighbors are always {0, +1, +W, +W+1} from one base.
__global__ __launch_bounds__(128) void points_kernel(
    const float* __restrict__ cq, const float* __restrict__ refp,
    const float* __restrict__ Woff, const float* __restrict__ boff,
    float4* __restrict__ rec_w, int* __restrict__ rec_i) {
    int b = blockIdx.x;
    __shared__ float4 q[NC / 4];
    __shared__ float offs[2 * NP];
    if (threadIdx.x < NC / 4)
        q[threadIdx.x] = ((const float4*)(cq + b * NC))[threadIdx.x];
    __syncthreads();
    int j = threadIdx.x;
    if (j < 2 * NP) {
        const float4* w = (const float4*)(Woff + j * NC);
        float acc = 0.f;
#pragma unroll
        for (int k = 0; k < NC / 4; ++k) {
            float4 a = q[k], bb = w[k];
            acc = fmaf(a.x, bb.x, acc);
            acc = fmaf(a.y, bb.y, acc);
            acc = fmaf(a.z, bb.z, acc);
            acc = fmaf(a.w, bb.w, acc);
        }
        offs[j] = acc + boff[j];
    }
    __syncthreads();
    int p = threadIdx.x;
    if (p < NP) {
        float sx = offs[2 * p + 0] + refp[b * 2 + 0];
        float sy = offs[2 * p + 1] + refp[b * 2 + 1];
        // grid = 2*s - 1 ; pix = ((g+1)*size - 1)/2 = s*size - 0.5 ; border clamp
        float x = fminf(fmaxf(sx * (float)WW - 0.5f, 0.f), (float)(WW - 1));
        float y = fminf(fmaxf(sy * (float)HH - 0.5f, 0.f), (float)(HH - 1));
        int x0 = min((int)floorf(x), WW - 2);
        int y0 = min((int)floorf(y), HH - 2);
        float wx = x - (float)x0, wy = y - (float)y0;
        rec_w[b * NP + p] = make_float4((1.f - wx) * (1.f - wy), wx * (1.f - wy),
                                        (1.f - wx) * wy, wx * wy);
        rec_i[b * NP + p] = y0 * WW + x0;
    }
}

// Kernel 2: bilinear gather, 1 thread per (image, point).
// block = 576 = 16 whole images x 36 points: no image split across blocks;
// p varies fastest so a wave's lanes share ~2 images -> L1 line reuse; record
// loads broadcast across each 36-lane point group. One base address per map,
// 4 loads with immediate offsets 0/4/160/164.
__global__ __launch_bounds__(BLK) void sample_kernel(
    const float* __restrict__ fmap, const float* __restrict__ pmap,
    const float4* __restrict__ rec_w, const int* __restrict__ rec_i,
    float* __restrict__ out) {
    int t = threadIdx.x;            // 0..575
    int ib = t / NP;                // image-in-block 0..15
    int p = t - ib * NP;            // 0..35
    int img = blockIdx.x * IPB + ib; // b*256 + c
    int b = img >> 8;

    float4 w = rec_w[b * NP + p];
    int i00 = rec_i[b * NP + p];

    const float* f = fmap + (long)img * (HH * WW) + i00;
    const float* g = pmap + (long)img * (HH * WW) + i00;

    float f00 = f[0], f01 = f[1], f10 = f[WW], f11 = f[WW + 1];
    float g00 = g[0], g01 = g[1], g10 = g[WW], g11 = g[WW + 1];

    float vf = f00 * w.x + f01 * w.y + f10 * w.z + f11 * w.w;
    float vg = g00 * w.x + g01 * w.y + g10 * w.z + g11 * w.w;

    long oidx = (long)img * NP + p;
    out[oidx] = vf;
    out[(long)NB * NC * NP + oidx] = vg;
}

extern "C" void kernel_launch(void* const* d_in, const int* in_sizes, int n_in,
                              void* d_out, int out_size, void* d_ws, size_t ws_size,
                              hipStream_t stream) {
    const float* cq   = (const float*)d_in[0];  // (128, 256)
    const float* refp = (const float*)d_in[1];  // (128, 2)
    const float* fmap = (const float*)d_in[2];  // (128, 256, 1600)
    const float* pmap = (const float*)d_in[3];  // (128, 256, 1600)
    const float* Woff = (const float*)d_in[4];  // (72, 256)
    const float* boff = (const float*)d_in[5];  // (72,)
    float* out = (float*)d_out;

    float4* rec_w = (float4*)d_ws;                       // 128*36*16 B
    int*    rec_i = (int*)((char*)d_ws + NB * NP * 16);  // 128*36*4 B

    points_kernel<<<NB, 128, 0, stream>>>(cq, refp, Woff, boff, rec_w, rec_i);

    // 65536 images / 16 per block = 4096 blocks of 576 threads.
    sample_kernel<<<(NB * NC) / IPB, BLK, 0, stream>>>(fmap, pmap, rec_w, rec_i, out);
}